// Round 11
// baseline (206.259 us; speedup 1.0000x reference)
//
#include <hip/hip_runtime.h>

#define DIM 128
#define BM 128
#define BK 32
#define BINSZ 128      // nodes per coarse bin (== BM: gemm block == bin)
#define EPB 2048       // edges per histogram/scatter block
#define AGS 136        // Agg LDS row stride in shorts (128+8 -> 4-bank shift)

typedef __attribute__((ext_vector_type(8))) short short8;
typedef __attribute__((ext_vector_type(4))) float f32x4;

// bf16 helpers (RNE), values are finite.
__device__ __forceinline__ unsigned short f2bf(float f) {
    unsigned int b = __float_as_uint(f);
    return (unsigned short)((b + 0x7fffu + ((b >> 16) & 1u)) >> 16);
}
__device__ __forceinline__ float bf_lo(unsigned int u) { return __uint_as_float(u << 16); }
__device__ __forceinline__ float bf_hi(unsigned int u) { return __uint_as_float(u & 0xffff0000u); }
__device__ __forceinline__ unsigned int pack2(float a, float b) {
    return (unsigned int)f2bf(a) | ((unsigned int)f2bf(b) << 16);
}
__device__ __forceinline__ uint2 pack4(float4 v) {
    uint2 r; r.x = pack2(v.x, v.y); r.y = pack2(v.z, v.w); return r;
}

// ---------------------------------------------------------------------------
// K1: fused convert (x->bf16, W->bf16) + per-block dual histogram.
// Blocks [0,NAB) do the histogram; the rest stream-convert. Also zeroes done.
// ---------------------------------------------------------------------------
__global__ __launch_bounds__(256) void convert_hist_kernel(
        const float4* __restrict__ x4, const float4* __restrict__ W4,
        const int* __restrict__ senders, const int* __restrict__ receivers,
        uint2* __restrict__ xb4, uint2* __restrict__ Wb4,
        int* __restrict__ Hr, int* __restrict__ Hs, int* __restrict__ done,
        int nx4, int nw4, int E, int nbin, int NAB) {
    if ((int)blockIdx.x < NAB) {
        __shared__ int hr[512], hs[512];
        int t = threadIdx.x;
        if (blockIdx.x == 0 && t == 0) *done = 0;
        for (int b = t; b < nbin; b += 256) { hr[b] = 0; hs[b] = 0; }
        __syncthreads();
        int base = blockIdx.x * EPB;
        for (int k = 0; k < EPB; k += 256) {
            int e = base + k + t;
            if (e < E) {
                atomicAdd(&hr[receivers[e] >> 7], 1);
                atomicAdd(&hs[senders[e] >> 7], 1);
            }
        }
        __syncthreads();
        size_t ho = (size_t)blockIdx.x * nbin;
        for (int b = t; b < nbin; b += 256) { Hr[ho + b] = hr[b]; Hs[ho + b] = hs[b]; }
    } else {
        int i = ((int)blockIdx.x - NAB) * 256 + threadIdx.x;
        if (i < nx4) xb4[i] = pack4(x4[i]);
        if (i < nw4) Wb4[i] = pack4(W4[i]);
    }
}

// ---------------------------------------------------------------------------
// K2: per-bin scan over blocks (H -> exclusive prefix + totals), fused with
// the base scan: the LAST block to finish (completion counter) scans the
// totals into base_r/base_s. Release = tot store + threadfence + atomicAdd
// by the same thread; acquire = atomicAdd(p,0) RMW reads (XCD-coherent).
// ---------------------------------------------------------------------------
__global__ __launch_bounds__(512) void scan_kernel(
        int* __restrict__ Hr, int* __restrict__ Hs,
        int* __restrict__ tot_r, int* __restrict__ tot_s,
        int* __restrict__ base_r, int* __restrict__ base_s,
        int* __restrict__ row_start, int* __restrict__ done,
        int NAB, int nbin, int N, int E) {
    __shared__ int sr[512], ss[512];
    __shared__ int rank_sh;
    int b = blockIdx.x, t = threadIdx.x;
    int vr = (t < NAB) ? Hr[(size_t)t * nbin + b] : 0;
    int vs = (t < NAB) ? Hs[(size_t)t * nbin + b] : 0;
    sr[t] = vr; ss[t] = vs;
    __syncthreads();
    for (int off = 1; off < 512; off <<= 1) {
        int ur = (t >= off) ? sr[t - off] : 0;
        int us = (t >= off) ? ss[t - off] : 0;
        __syncthreads();
        sr[t] += ur; ss[t] += us;
        __syncthreads();
    }
    if (t < NAB) {
        Hr[(size_t)t * nbin + b] = sr[t] - vr;   // exclusive prefix
        Hs[(size_t)t * nbin + b] = ss[t] - vs;
    }
    if (t == 511) {
        tot_r[b] = sr[511]; tot_s[b] = ss[511];
        __threadfence();
        rank_sh = atomicAdd(done, 1);
    }
    __syncthreads();
    if (rank_sh == (int)gridDim.x - 1) {
        int wr2 = (t < nbin) ? atomicAdd(&tot_r[t], 0) : 0;   // coherent read
        int ws2 = (t < nbin) ? atomicAdd(&tot_s[t], 0) : 0;
        sr[t] = wr2; ss[t] = ws2;
        __syncthreads();
        for (int off = 1; off < 512; off <<= 1) {
            int ur = (t >= off) ? sr[t - off] : 0;
            int us = (t >= off) ? ss[t - off] : 0;
            __syncthreads();
            sr[t] += ur; ss[t] += us;
            __syncthreads();
        }
        if (t < nbin) { base_r[t] = sr[t] - wr2; base_s[t] = ss[t] - ws2; }
        if (t == 0) { base_r[nbin] = E; base_s[nbin] = E; row_start[N] = E; }
    }
}

// ---------------------------------------------------------------------------
// K3: scatter into coarse buckets. Cursors = base[b] + P[blk][b]; LDS atomics
// only, plain global stores. bucket_s is ushort (senders < 65536).
// ---------------------------------------------------------------------------
__global__ __launch_bounds__(256) void scatter_kernel(
        const int* __restrict__ senders, const int* __restrict__ receivers,
        const int* __restrict__ Hr, const int* __restrict__ Hs,
        const int* __restrict__ base_r, const int* __restrict__ base_s,
        unsigned int* __restrict__ bucket_r, unsigned short* __restrict__ bucket_s,
        int E, int nbin) {
    __shared__ int br_[512], bs_[512];
    int t = threadIdx.x;
    size_t ho = (size_t)blockIdx.x * nbin;
    for (int b = t; b < nbin; b += 256) {
        br_[b] = base_r[b] + Hr[ho + b];
        bs_[b] = base_s[b] + Hs[ho + b];
    }
    __syncthreads();
    int base = blockIdx.x * EPB;
    for (int k = 0; k < EPB; k += 256) {
        int e = base + k + t;
        if (e < E) {
            int s = senders[e], r = receivers[e];
            int pr = atomicAdd(&br_[r >> 7], 1);
            bucket_r[pr] = ((unsigned int)(r & 127) << 16) | (unsigned int)s;
            int ps = atomicAdd(&bs_[s >> 7], 1);
            bucket_s[ps] = (unsigned short)s;
        }
    }
}

// ---------------------------------------------------------------------------
// K4: fused fine pass (one block per bin): receiver fine-sort -> row_start +
// edge_src; sender fine-count (LDS) -> fs; prescale xs = x_bf * rsqrt(deg+1).
// ---------------------------------------------------------------------------
__global__ __launch_bounds__(256) void fine_kernel(
        const unsigned int* __restrict__ bucket_r,
        const unsigned short* __restrict__ bucket_s,
        const int* __restrict__ base_r,
        const int* __restrict__ base_s,
        const uint2* __restrict__ xb2,     // [N][32]
        int* __restrict__ edge_src,
        int* __restrict__ row_start,
        float* __restrict__ fs,
        uint2* __restrict__ xs2,           // [NP][32]
        int N) {
    __shared__ int fine[BINSZ], fstart[BINSZ], cs[BINSZ];
    __shared__ float scs[BINSZ];
    int b = blockIdx.x, t = threadIdx.x;
    if (t < BINSZ) { fine[t] = 0; cs[t] = 0; }
    __syncthreads();

    int loR = base_r[b], hiR = base_r[b + 1];
    int loS = base_s[b], hiS = base_s[b + 1];
    for (int i = loR + t; i < hiR; i += 256)
        atomicAdd(&fine[bucket_r[i] >> 16], 1);
    for (int i = loS + t; i < hiS; i += 256)
        atomicAdd(&cs[bucket_s[i] & 127], 1);
    __syncthreads();

    if (t < BINSZ) fstart[t] = fine[t];
    __syncthreads();
    for (int off = 1; off < BINSZ; off <<= 1) {
        int u = (t < BINSZ && t >= off) ? fstart[t - off] : 0;
        __syncthreads();
        if (t < BINSZ) fstart[t] += u;
        __syncthreads();
    }
    if (t < BINSZ) {
        int excl = fstart[t] - fine[t];
        int node = b * BINSZ + t;
        float od = (float)(fine[t] + 1);
        float sc = rsqrtf(od);
        scs[t] = sc;
        if (node < N) {
            row_start[node] = loR + excl;
            fs[node] = rsqrtf((float)(cs[t] + 1)) / od;
        }
        fstart[t] = excl;   // becomes the scatter cursor
    }
    __syncthreads();

    for (int i = loR + t; i < hiR; i += 256) {
        unsigned int u = bucket_r[i];
        int pos = atomicAdd(&fstart[u >> 16], 1);
        edge_src[loR + pos] = (int)(u & 0xFFFFu);
    }

    // Prescale this bin's 128 rows: 128 x 32 uint2.
    int nrow0 = b * BINSZ;
    for (int idx = t; idx < BINSZ * 32; idx += 256) {
        int row = idx >> 5, c = idx & 31;
        int node = nrow0 + row;
        if (node < N) {
            float sc = scs[row];
            uint2 u = xb2[(size_t)node * 32 + c];
            uint2 o;
            o.x = pack2(bf_lo(u.x) * sc, bf_hi(u.x) * sc);
            o.y = pack2(bf_lo(u.y) * sc, bf_hi(u.y) * sc);
            xs2[(size_t)node * 32 + c] = o;
        }
    }
}

// ---------------------------------------------------------------------------
// K5: fused gather + MFMA GEMM. Block = 128 rows (one bin), 512 threads.
// Phase 1: each wave gathers 16 rows' agg into LDS Agg (bf16, stride AGS).
// Phase 2: out = [x_bf | Agg] @ W_bf^T + b; A from LDS directly for kt>=4.
// ---------------------------------------------------------------------------
__global__ __launch_bounds__(512) void gather_gemm_kernel(
        const unsigned short* __restrict__ x_bf,   // [NP][128]
        const unsigned int* __restrict__ xs,       // [NP][64] uints
        const int* __restrict__ edge_src,
        const int* __restrict__ row_start,         // [N+1]
        const float* __restrict__ fs,              // [N]
        const unsigned short* __restrict__ W_bf,   // [128][256]
        const float* __restrict__ bias,
        float* __restrict__ out, int N) {
    __shared__ unsigned short Agg[BM * AGS];   // 34 KB
    __shared__ unsigned short As[BM * BK];     // 8 KB
    __shared__ unsigned short Bs[DIM * BK];    // 8 KB

    int t = threadIdx.x, lane = t & 63, w = t >> 6;
    int row0 = blockIdx.x * BM;

    // ---- Phase 1: gather 16 rows per wave into Agg ----
    for (int i = 0; i < 16; i++) {
        int row = w * 16 + i;
        int n = row0 + row;
        float ax = 0.f, ay = 0.f;
        if (n < N) {
            int start = row_start[n];
            int deg   = row_start[n + 1] - start;
            for (int base = 0; base < deg; base += 64) {
                int cnt = deg - base; if (cnt > 64) cnt = 64;
                int src = 0;
                if (lane < cnt) src = edge_src[start + base + lane];
                int j = 0;
                for (; j + 8 <= cnt; j += 8) {
                    int ssx[8]; unsigned int uu[8];
#pragma unroll
                    for (int q = 0; q < 8; q++) ssx[q] = __shfl(src, j + q);
#pragma unroll
                    for (int q = 0; q < 8; q++) uu[q] = xs[(size_t)ssx[q] * 64 + lane];
#pragma unroll
                    for (int q = 0; q < 8; q++) { ax += bf_lo(uu[q]); ay += bf_hi(uu[q]); }
                }
                for (; j < cnt; j++) {
                    int s = __shfl(src, j);
                    unsigned int u = xs[(size_t)s * 64 + lane];
                    ax += bf_lo(u); ay += bf_hi(u);
                }
            }
            float f = fs[n];
            unsigned int u = xs[(size_t)n * 64 + lane];
            ax = (ax + bf_lo(u)) * f;
            ay = (ay + bf_hi(u)) * f;
        }
        *(unsigned int*)&Agg[row * AGS + 2 * lane] = pack2(ax, ay);
    }
    __syncthreads();

    // ---- Phase 2: GEMM ----
    int wr = w >> 2, wc = w & 3;
    f32x4 acc[4][2];
#pragma unroll
    for (int i = 0; i < 4; i++)
#pragma unroll
        for (int j = 0; j < 2; j++) acc[i][j] = (f32x4){0.f, 0.f, 0.f, 0.f};

    for (int kt = 0; kt < 8; kt++) {
        if (kt < 4) {   // stage A from x_bf (rows >= N hold finite poison; ok)
            int row = t >> 2, ch = t & 3;
            uint4 v = *(const uint4*)&x_bf[(size_t)(row0 + row) * 128 + kt * BK + ch * 8];
            *(uint4*)&As[row * BK + ch * 8] = v;
        }
        {   // stage B slice from W_bf
            int n2 = t >> 2, ch = t & 3;
            uint4 v = *(const uint4*)&W_bf[(size_t)n2 * 256 + kt * BK + ch * 8];
            *(uint4*)&Bs[n2 * BK + ch * 8] = v;
        }
        __syncthreads();

        short8 a[4], b2[2];
#pragma unroll
        for (int i = 0; i < 4; i++) {
            int arow = wr * 64 + i * 16 + (lane & 15);
            a[i] = (kt < 4)
                ? *(const short8*)&As[arow * BK + (lane >> 4) * 8]
                : *(const short8*)&Agg[arow * AGS + (kt - 4) * 32 + (lane >> 4) * 8];
        }
#pragma unroll
        for (int j = 0; j < 2; j++)
            b2[j] = *(const short8*)&Bs[(wc * 32 + j * 16 + (lane & 15)) * BK + (lane >> 4) * 8];
#pragma unroll
        for (int i = 0; i < 4; i++)
#pragma unroll
            for (int j = 0; j < 2; j++)
                acc[i][j] = __builtin_amdgcn_mfma_f32_16x16x32_bf16(a[i], b2[j], acc[i][j], 0, 0, 0);
        __syncthreads();
    }

    int cq = lane >> 4;
    int cl = lane & 15;
#pragma unroll
    for (int j = 0; j < 2; j++) {
        int col = wc * 32 + j * 16 + cl;
        float bb = bias[col];
#pragma unroll
        for (int i = 0; i < 4; i++) {
            int rbase = row0 + wr * 64 + i * 16 + cq * 4;
#pragma unroll
            for (int r = 0; r < 4; r++) {
                int row = rbase + r;
                if (row < N) out[(size_t)row * DIM + col] = acc[i][j][r] + bb;
            }
        }
    }
}

// ---------------------------------------------------------------------------
// Launch
// ---------------------------------------------------------------------------
extern "C" void kernel_launch(void* const* d_in, const int* in_sizes, int n_in,
                              void* d_out, int out_size, void* d_ws, size_t ws_size,
                              hipStream_t stream) {
    const float* x         = (const float*)d_in[0];
    const int*   senders   = (const int*)d_in[1];
    const int*   receivers = (const int*)d_in[2];
    const float* W         = (const float*)d_in[4];
    const float* bias      = (const float*)d_in[5];
    float*       out       = (float*)d_out;

    int N    = in_sizes[0] / DIM;              // 50000
    int E    = in_sizes[1];                    // 625000
    int nbin = (N + BINSZ - 1) / BINSZ;        // 391  (<= 512)
    int NAB  = (E + EPB - 1) / EPB;            // 306  (<= 512)
    int NP   = ((N + BM - 1) / BM) * BM;       // 50048

    // Workspace layout, 256B-aligned chunks. Total ~33 MB (no agg array:
    // it lives in LDS inside gather_gemm now). No memset needed (done is
    // zeroed by K1).
    char* ws = (char*)d_ws;
    size_t off = 0;
    #define WS_ALLOC(ptrtype, name, bytes) \
        ptrtype name = (ptrtype)(ws + off); off += (((size_t)(bytes)) + 255) & ~(size_t)255;
    WS_ALLOC(int*,            tot_r,     (size_t)nbin * 4)
    WS_ALLOC(int*,            tot_s,     (size_t)nbin * 4)
    WS_ALLOC(int*,            base_r,    (size_t)(nbin + 1) * 4)
    WS_ALLOC(int*,            base_s,    (size_t)(nbin + 1) * 4)
    WS_ALLOC(int*,            row_start, (size_t)(N + 1) * 4)
    WS_ALLOC(float*,          fs,        (size_t)N * 4)
    WS_ALLOC(int*,            done,      256)
    WS_ALLOC(int*,            edge_src,  (size_t)E * 4)
    WS_ALLOC(unsigned short*, x_bf,      (size_t)NP * DIM * 2)
    WS_ALLOC(unsigned short*, xs_bf,     (size_t)NP * DIM * 2)
    WS_ALLOC(unsigned short*, W_bf,      (size_t)DIM * 256 * 2)
    WS_ALLOC(unsigned int*,   bucket_r,  (size_t)E * 4)
    WS_ALLOC(unsigned short*, bucket_s,  (size_t)E * 2)
    WS_ALLOC(int*,            Hr,        (size_t)NAB * nbin * 4)
    WS_ALLOC(int*,            Hs,        (size_t)NAB * nbin * 4)
    #undef WS_ALLOC

    int nx4 = N * 32;          // float4 count of x
    int nw4 = DIM * 256 / 4;   // 8192
    int conv_blocks = (nx4 + 255) / 256;

    convert_hist_kernel<<<NAB + conv_blocks, 256, 0, stream>>>(
        (const float4*)x, (const float4*)W, senders, receivers,
        (uint2*)x_bf, (uint2*)W_bf, Hr, Hs, done, nx4, nw4, E, nbin, NAB);
    scan_kernel<<<nbin, 512, 0, stream>>>(Hr, Hs, tot_r, tot_s, base_r, base_s,
                                          row_start, done, NAB, nbin, N, E);
    scatter_kernel<<<NAB, 256, 0, stream>>>(senders, receivers, Hr, Hs,
                                            base_r, base_s, bucket_r, bucket_s, E, nbin);
    fine_kernel<<<nbin, 256, 0, stream>>>(bucket_r, bucket_s, base_r, base_s,
                                          (const uint2*)x_bf, edge_src, row_start,
                                          fs, (uint2*)xs_bf, N);
    gather_gemm_kernel<<<(N + BM - 1) / BM, 512, 0, stream>>>(
        x_bf, (const unsigned int*)xs_bf, edge_src, row_start, fs,
        W_bf, bias, out, N);
}

// Round 12
// 186.430 us; speedup vs baseline: 1.1064x; 1.1064x over previous
//
#include <hip/hip_runtime.h>

#define DIM 128
#define BM 128
#define BK 32
#define BINSZ 128      // nodes per coarse bin
#define EPB 2048       // edges per histogram/scatter block

typedef __attribute__((ext_vector_type(8))) short short8;
typedef __attribute__((ext_vector_type(4))) float f32x4;

// bf16 helpers (RNE), values are finite.
__device__ __forceinline__ unsigned short f2bf(float f) {
    unsigned int b = __float_as_uint(f);
    return (unsigned short)((b + 0x7fffu + ((b >> 16) & 1u)) >> 16);
}
__device__ __forceinline__ float bf_lo(unsigned int u) { return __uint_as_float(u << 16); }
__device__ __forceinline__ float bf_hi(unsigned int u) { return __uint_as_float(u & 0xffff0000u); }
__device__ __forceinline__ unsigned int pack2(float a, float b) {
    return (unsigned int)f2bf(a) | ((unsigned int)f2bf(b) << 16);
}
__device__ __forceinline__ uint2 pack4(float4 v) {
    uint2 r; r.x = pack2(v.x, v.y); r.y = pack2(v.z, v.w); return r;
}

// ---------------------------------------------------------------------------
// K1: fused convert (x->bf16, W->bf16) + per-block dual histogram.
// Blocks [0,NAB) histogram; the rest stream-convert. Also zeroes done.
// ---------------------------------------------------------------------------
__global__ __launch_bounds__(256) void convert_hist_kernel(
        const float4* __restrict__ x4, const float4* __restrict__ W4,
        const int* __restrict__ senders, const int* __restrict__ receivers,
        uint2* __restrict__ xb4, uint2* __restrict__ Wb4,
        int* __restrict__ Hr, int* __restrict__ Hs, int* __restrict__ done,
        int nx4, int nw4, int E, int nbin, int NAB) {
    if ((int)blockIdx.x < NAB) {
        __shared__ int hr[512], hs[512];
        int t = threadIdx.x;
        if (blockIdx.x == 0 && t == 0) *done = 0;
        for (int b = t; b < nbin; b += 256) { hr[b] = 0; hs[b] = 0; }
        __syncthreads();
        int base = blockIdx.x * EPB;
        for (int k = 0; k < EPB; k += 256) {
            int e = base + k + t;
            if (e < E) {
                atomicAdd(&hr[receivers[e] >> 7], 1);
                atomicAdd(&hs[senders[e] >> 7], 1);
            }
        }
        __syncthreads();
        size_t ho = (size_t)blockIdx.x * nbin;
        for (int b = t; b < nbin; b += 256) { Hr[ho + b] = hr[b]; Hs[ho + b] = hs[b]; }
    } else {
        int i = ((int)blockIdx.x - NAB) * 256 + threadIdx.x;
        if (i < nx4) xb4[i] = pack4(x4[i]);
        if (i < nw4) Wb4[i] = pack4(W4[i]);
    }
}

// ---------------------------------------------------------------------------
// K2: per-bin scan over blocks (H -> exclusive prefix + totals), fused with
// the base scan via completion counter (last block scans totals).
// ---------------------------------------------------------------------------
__global__ __launch_bounds__(512) void scan_kernel(
        int* __restrict__ Hr, int* __restrict__ Hs,
        int* __restrict__ tot_r, int* __restrict__ tot_s,
        int* __restrict__ base_r, int* __restrict__ base_s,
        int* __restrict__ row_start, int* __restrict__ done,
        int NAB, int nbin, int N, int E) {
    __shared__ int sr[512], ss[512];
    __shared__ int rank_sh;
    int b = blockIdx.x, t = threadIdx.x;
    int vr = (t < NAB) ? Hr[(size_t)t * nbin + b] : 0;
    int vs = (t < NAB) ? Hs[(size_t)t * nbin + b] : 0;
    sr[t] = vr; ss[t] = vs;
    __syncthreads();
    for (int off = 1; off < 512; off <<= 1) {
        int ur = (t >= off) ? sr[t - off] : 0;
        int us = (t >= off) ? ss[t - off] : 0;
        __syncthreads();
        sr[t] += ur; ss[t] += us;
        __syncthreads();
    }
    if (t < NAB) {
        Hr[(size_t)t * nbin + b] = sr[t] - vr;   // exclusive prefix
        Hs[(size_t)t * nbin + b] = ss[t] - vs;
    }
    if (t == 511) {
        tot_r[b] = sr[511]; tot_s[b] = ss[511];
        __threadfence();
        rank_sh = atomicAdd(done, 1);
    }
    __syncthreads();
    if (rank_sh == (int)gridDim.x - 1) {
        int wr2 = (t < nbin) ? atomicAdd(&tot_r[t], 0) : 0;   // coherent read
        int ws2 = (t < nbin) ? atomicAdd(&tot_s[t], 0) : 0;
        sr[t] = wr2; ss[t] = ws2;
        __syncthreads();
        for (int off = 1; off < 512; off <<= 1) {
            int ur = (t >= off) ? sr[t - off] : 0;
            int us = (t >= off) ? ss[t - off] : 0;
            __syncthreads();
            sr[t] += ur; ss[t] += us;
            __syncthreads();
        }
        if (t < nbin) { base_r[t] = sr[t] - wr2; base_s[t] = ss[t] - ws2; }
        if (t == 0) { base_r[nbin] = E; base_s[nbin] = E; row_start[N] = E; }
    }
}

// ---------------------------------------------------------------------------
// K3: scatter into coarse buckets (LDS cursors, plain global stores).
// ---------------------------------------------------------------------------
__global__ __launch_bounds__(256) void scatter_kernel(
        const int* __restrict__ senders, const int* __restrict__ receivers,
        const int* __restrict__ Hr, const int* __restrict__ Hs,
        const int* __restrict__ base_r, const int* __restrict__ base_s,
        unsigned int* __restrict__ bucket_r, unsigned short* __restrict__ bucket_s,
        int E, int nbin) {
    __shared__ int br_[512], bs_[512];
    int t = threadIdx.x;
    size_t ho = (size_t)blockIdx.x * nbin;
    for (int b = t; b < nbin; b += 256) {
        br_[b] = base_r[b] + Hr[ho + b];
        bs_[b] = base_s[b] + Hs[ho + b];
    }
    __syncthreads();
    int base = blockIdx.x * EPB;
    for (int k = 0; k < EPB; k += 256) {
        int e = base + k + t;
        if (e < E) {
            int s = senders[e], r = receivers[e];
            int pr = atomicAdd(&br_[r >> 7], 1);
            bucket_r[pr] = ((unsigned int)(r & 127) << 16) | (unsigned int)s;
            int ps = atomicAdd(&bs_[s >> 7], 1);
            bucket_s[ps] = (unsigned short)s;
        }
    }
}

// ---------------------------------------------------------------------------
// K4: fused fine pass (one block per bin): receiver fine-sort -> row_start +
// edge_src; sender fine-count -> fs; prescale xs = x_bf * rsqrt(deg+1).
// ---------------------------------------------------------------------------
__global__ __launch_bounds__(256) void fine_kernel(
        const unsigned int* __restrict__ bucket_r,
        const unsigned short* __restrict__ bucket_s,
        const int* __restrict__ base_r,
        const int* __restrict__ base_s,
        const uint2* __restrict__ xb2,     // [N][32]
        int* __restrict__ edge_src,
        int* __restrict__ row_start,
        float* __restrict__ fs,
        uint2* __restrict__ xs2,           // [NP][32]
        int N) {
    __shared__ int fine[BINSZ], fstart[BINSZ], cs[BINSZ];
    __shared__ float scs[BINSZ];
    int b = blockIdx.x, t = threadIdx.x;
    if (t < BINSZ) { fine[t] = 0; cs[t] = 0; }
    __syncthreads();

    int loR = base_r[b], hiR = base_r[b + 1];
    int loS = base_s[b], hiS = base_s[b + 1];
    for (int i = loR + t; i < hiR; i += 256)
        atomicAdd(&fine[bucket_r[i] >> 16], 1);
    for (int i = loS + t; i < hiS; i += 256)
        atomicAdd(&cs[bucket_s[i] & 127], 1);
    __syncthreads();

    if (t < BINSZ) fstart[t] = fine[t];
    __syncthreads();
    for (int off = 1; off < BINSZ; off <<= 1) {
        int u = (t < BINSZ && t >= off) ? fstart[t - off] : 0;
        __syncthreads();
        if (t < BINSZ) fstart[t] += u;
        __syncthreads();
    }
    if (t < BINSZ) {
        int excl = fstart[t] - fine[t];
        int node = b * BINSZ + t;
        float od = (float)(fine[t] + 1);
        float sc = rsqrtf(od);
        scs[t] = sc;
        if (node < N) {
            row_start[node] = loR + excl;
            fs[node] = rsqrtf((float)(cs[t] + 1)) / od;
        }
        fstart[t] = excl;   // becomes the scatter cursor
    }
    __syncthreads();

    for (int i = loR + t; i < hiR; i += 256) {
        unsigned int u = bucket_r[i];
        int pos = atomicAdd(&fstart[u >> 16], 1);
        edge_src[loR + pos] = (int)(u & 0xFFFFu);
    }

    // Prescale this bin's 128 rows: 128 x 32 uint2.
    int nrow0 = b * BINSZ;
    for (int idx = t; idx < BINSZ * 32; idx += 256) {
        int row = idx >> 5, c = idx & 31;
        int node = nrow0 + row;
        if (node < N) {
            float sc = scs[row];
            uint2 u = xb2[(size_t)node * 32 + c];
            uint2 o;
            o.x = pack2(bf_lo(u.x) * sc, bf_hi(u.x) * sc);
            o.y = pack2(bf_lo(u.y) * sc, bf_hi(u.y) * sc);
            xs2[(size_t)node * 32 + c] = o;
        }
    }
}

// ---------------------------------------------------------------------------
// K5: gather (standalone — needs max TLP to hide random-fabric latency).
// agg[n] = (sum_{src in CSR[n]} xs[src] + xs[n]) * fs[n]. One wave per node.
// ---------------------------------------------------------------------------
__global__ __launch_bounds__(256) void gather_kernel(
        const unsigned int* __restrict__ xs,     // [NP][64]
        const int* __restrict__ edge_src,
        const int* __restrict__ row_start,       // [N+1]
        const float* __restrict__ fs,            // [N]
        unsigned int* __restrict__ aggb,         // [NP][64]
        int N) {
    int lane = threadIdx.x & 63;
    int n = (blockIdx.x * blockDim.x + threadIdx.x) >> 6;
    if (n >= N) return;

    int start = row_start[n];
    int deg   = row_start[n + 1] - start;
    float ax = 0.f, ay = 0.f;

    for (int base = 0; base < deg; base += 64) {
        int cnt = deg - base; if (cnt > 64) cnt = 64;
        int src = 0;
        if (lane < cnt) src = edge_src[start + base + lane];
        int j = 0;
        for (; j + 8 <= cnt; j += 8) {
            int ss[8]; unsigned int uu[8];
#pragma unroll
            for (int q = 0; q < 8; q++) ss[q] = __shfl(src, j + q);
#pragma unroll
            for (int q = 0; q < 8; q++) uu[q] = xs[(size_t)ss[q] * 64 + lane];
#pragma unroll
            for (int q = 0; q < 8; q++) { ax += bf_lo(uu[q]); ay += bf_hi(uu[q]); }
        }
        for (; j < cnt; j++) {
            int s = __shfl(src, j);
            unsigned int u = xs[(size_t)s * 64 + lane];
            ax += bf_lo(u); ay += bf_hi(u);
        }
    }

    float f = fs[n];
    unsigned int u = xs[(size_t)n * 64 + lane];
    ax = (ax + bf_lo(u)) * f;
    ay = (ay + bf_hi(u)) * f;
    aggb[(size_t)n * 64 + lane] = pack2(ax, ay);
}

// ---------------------------------------------------------------------------
// K6: MFMA bf16 GEMM, 512 threads: out = [x_bf | agg_bf] @ W_bf^T + b.
// Block 128x128, 8 waves in 2x4; each wave 4x2 tiles of 16x16x32 mfma.
// ---------------------------------------------------------------------------
__global__ __launch_bounds__(512) void gemm_kernel(
        const unsigned short* __restrict__ x_bf,   // [NP][128]
        const unsigned short* __restrict__ agg_bf, // [NP][128]
        const unsigned short* __restrict__ W_bf,   // [128][256]
        const float* __restrict__ bias,
        float* __restrict__ out, int N) {
    __shared__ unsigned short As[BM * BK];
    __shared__ unsigned short Bs[DIM * BK];

    int t    = threadIdx.x;
    int lane = t & 63;
    int w    = t >> 6;           // 0..7
    int wr   = w >> 2, wc = w & 3;
    int row0 = blockIdx.x * BM;

    f32x4 acc[4][2];
#pragma unroll
    for (int i = 0; i < 4; i++)
#pragma unroll
        for (int j = 0; j < 2; j++) acc[i][j] = (f32x4){0.f, 0.f, 0.f, 0.f};

    for (int kt = 0; kt < 8; kt++) {
        const unsigned short* src = (kt < 4) ? x_bf : agg_bf;
        int k0 = (kt & 3) * BK;
        {   // stage A: 128 rows x 32 k
            int row = t >> 2, ch = t & 3;
            uint4 v = *(const uint4*)&src[(size_t)(row0 + row) * 128 + k0 + ch * 8];
            *(uint4*)&As[row * BK + ch * 8] = v;
        }
        {   // stage B: 128 n x 32 k
            int n = t >> 2, ch = t & 3;
            uint4 v = *(const uint4*)&W_bf[(size_t)n * 256 + kt * BK + ch * 8];
            *(uint4*)&Bs[n * BK + ch * 8] = v;
        }
        __syncthreads();

        short8 a[4], b[2];
#pragma unroll
        for (int i = 0; i < 4; i++)
            a[i] = *(const short8*)&As[(wr * 64 + i * 16 + (lane & 15)) * BK + (lane >> 4) * 8];
#pragma unroll
        for (int j = 0; j < 2; j++)
            b[j] = *(const short8*)&Bs[(wc * 32 + j * 16 + (lane & 15)) * BK + (lane >> 4) * 8];
#pragma unroll
        for (int i = 0; i < 4; i++)
#pragma unroll
            for (int j = 0; j < 2; j++)
                acc[i][j] = __builtin_amdgcn_mfma_f32_16x16x32_bf16(a[i], b[j], acc[i][j], 0, 0, 0);
        __syncthreads();
    }

    int cq = lane >> 4;
    int cl = lane & 15;
#pragma unroll
    for (int j = 0; j < 2; j++) {
        int col = wc * 32 + j * 16 + cl;
        float bb = bias[col];
#pragma unroll
        for (int i = 0; i < 4; i++) {
            int rbase = row0 + wr * 64 + i * 16 + cq * 4;
#pragma unroll
            for (int r = 0; r < 4; r++) {
                int row = rbase + r;
                if (row < N) out[(size_t)row * DIM + col] = acc[i][j][r] + bb;
            }
        }
    }
}

// ---------------------------------------------------------------------------
// Launch
// ---------------------------------------------------------------------------
extern "C" void kernel_launch(void* const* d_in, const int* in_sizes, int n_in,
                              void* d_out, int out_size, void* d_ws, size_t ws_size,
                              hipStream_t stream) {
    const float* x         = (const float*)d_in[0];
    const int*   senders   = (const int*)d_in[1];
    const int*   receivers = (const int*)d_in[2];
    const float* W         = (const float*)d_in[4];
    const float* bias      = (const float*)d_in[5];
    float*       out       = (float*)d_out;

    int N    = in_sizes[0] / DIM;              // 50000
    int E    = in_sizes[1];                    // 625000
    int nbin = (N + BINSZ - 1) / BINSZ;        // 391  (<= 512)
    int NAB  = (E + EPB - 1) / EPB;            // 306  (<= 512)
    int NP   = ((N + BM - 1) / BM) * BM;       // 50048

    // Workspace ~41.4 MB (fits; R10-proven). Buckets + H alias agg_bf:
    // all dead before gather writes agg.
    char* ws = (char*)d_ws;
    size_t off = 0;
    #define WS_ALLOC(ptrtype, name, bytes) \
        ptrtype name = (ptrtype)(ws + off); off += (((size_t)(bytes)) + 255) & ~(size_t)255;
    WS_ALLOC(int*,            tot_r,     (size_t)nbin * 4)
    WS_ALLOC(int*,            tot_s,     (size_t)nbin * 4)
    WS_ALLOC(int*,            base_r,    (size_t)(nbin + 1) * 4)
    WS_ALLOC(int*,            base_s,    (size_t)(nbin + 1) * 4)
    WS_ALLOC(int*,            row_start, (size_t)(N + 1) * 4)
    WS_ALLOC(float*,          fs,        (size_t)N * 4)
    WS_ALLOC(int*,            done,      256)
    WS_ALLOC(int*,            edge_src,  (size_t)E * 4)
    WS_ALLOC(unsigned short*, x_bf,      (size_t)NP * DIM * 2)
    WS_ALLOC(unsigned short*, xs_bf,     (size_t)NP * DIM * 2)
    WS_ALLOC(unsigned short*, agg_bf,    (size_t)NP * DIM * 2)
    WS_ALLOC(unsigned short*, W_bf,      (size_t)DIM * 256 * 2)
    #undef WS_ALLOC

    // Aliases inside agg_bf (12.8 MB >= 2.5 + 1.25 + 0.48 + 0.48 MB):
    size_t eb = ((size_t)E * 4 + 255) & ~(size_t)255;
    size_t sb = ((size_t)E * 2 + 255) & ~(size_t)255;
    size_t hb = ((size_t)NAB * nbin * 4 + 255) & ~(size_t)255;
    unsigned int*   bucket_r = (unsigned int*)agg_bf;
    unsigned short* bucket_s = (unsigned short*)((char*)agg_bf + eb);
    int*            Hr       = (int*)((char*)agg_bf + eb + sb);
    int*            Hs       = (int*)((char*)agg_bf + eb + sb + hb);

    int nx4 = N * 32;          // float4 count of x
    int nw4 = DIM * 256 / 4;   // 8192
    int conv_blocks = (nx4 + 255) / 256;

    convert_hist_kernel<<<NAB + conv_blocks, 256, 0, stream>>>(
        (const float4*)x, (const float4*)W, senders, receivers,
        (uint2*)x_bf, (uint2*)W_bf, Hr, Hs, done, nx4, nw4, E, nbin, NAB);
    scan_kernel<<<nbin, 512, 0, stream>>>(Hr, Hs, tot_r, tot_s, base_r, base_s,
                                          row_start, done, NAB, nbin, N, E);
    scatter_kernel<<<NAB, 256, 0, stream>>>(senders, receivers, Hr, Hs,
                                            base_r, base_s, bucket_r, bucket_s, E, nbin);
    fine_kernel<<<nbin, 256, 0, stream>>>(bucket_r, bucket_s, base_r, base_s,
                                          (const uint2*)x_bf, edge_src, row_start,
                                          fs, (uint2*)xs_bf, N);
    gather_kernel<<<(N * 64 + 255) / 256, 256, 0, stream>>>(
        (const unsigned int*)xs_bf, edge_src, row_start, fs,
        (unsigned int*)agg_bf, N);
    gemm_kernel<<<(N + BM - 1) / BM, 512, 0, stream>>>(
        x_bf, agg_bf, W_bf, bias, out, N);
}